// Round 1
// baseline (180.339 us; speedup 1.0000x reference)
//
#include <hip/hip_runtime.h>

#define NHEADS 8
#define NB 512
#define NN 1000
#define DD 128
#define HH 128
#define SDIM 384   // D*CAT

// One block per batch element. 256 threads = 4 waves = 8 groups of 32 lanes.
// Group g handles rows n = g, g+8, ... Each lane owns a 4-wide d-slice.
__global__ __launch_bounds__(256) void attn_fused_kernel(
    const float* __restrict__ state_t,   // [B][384]
    const float* __restrict__ context,   // [B][N][128]
    const int*   __restrict__ mask,      // [B][N]  (nonzero = masked out)
    const float* __restrict__ Wq,        // [128][384]
    const float* __restrict__ Wk,        // [128][128]
    const float* __restrict__ Wv,        // [128][128]
    const float* __restrict__ Wfc,       // [128][128]
    float* __restrict__ out)             // [B][128]
{
    const int b = blockIdx.x;
    const int t = threadIdx.x;

    __shared__ float s_state[SDIM];
    __shared__ float s_q[HH];
    __shared__ float s_qw[NHEADS][DD];      // pre-scaled by (1/16)*log2(e)
    __shared__ float s_acc[8][NHEADS][DD];  // per-group partial accum (32 KB)
    __shared__ float s_den[8][NHEADS];
    __shared__ float s_ca[NHEADS][132];     // padded to kill 4-way conflicts
    __shared__ float s_out[HH];

    // ---- stage state_t[b] ----
    for (int i = t; i < SDIM; i += 256) s_state[i] = state_t[(size_t)b * SDIM + i];
    __syncthreads();

    // ---- q[r] = state . Wq[r]  (threads 0..127) ----
    if (t < HH) {
        const float* wq = Wq + (size_t)t * SDIM;
        float a = 0.f;
        #pragma unroll 4
        for (int c = 0; c < SDIM; ++c) a = fmaf(s_state[c], wq[c], a);
        s_q[t] = a;
    }
    __syncthreads();

    // ---- qw[h][d] = (1/16)*log2(e) * sum_j q[h*16+j] * Wk[h*16+j][d] ----
    {
        const int d  = t & 127;
        const int h0 = (t >> 7) * 4;
        const float sc = 0.0625f * 1.4426950408889634f;  // scale * log2(e)
        for (int hh = 0; hh < 4; ++hh) {
            const int h = h0 + hh;
            float a = 0.f;
            #pragma unroll
            for (int j = 0; j < 16; ++j)
                a = fmaf(s_q[h * 16 + j], Wk[(size_t)(h * 16 + j) * DD + d], a);
            s_qw[h][d] = a * sc;
        }
    }
    __syncthreads();

    // ---- main fused pass over context rows ----
    const int lane = t & 63;
    const int wv   = t >> 6;
    const int l32  = lane & 31;
    const int g    = wv * 2 + (lane >> 5);  // group 0..7
    const int d4   = l32 * 4;

    float qwr[NHEADS][4];
    #pragma unroll
    for (int h = 0; h < NHEADS; ++h)
        #pragma unroll
        for (int k = 0; k < 4; ++k)
            qwr[h][k] = s_qw[h][d4 + k];

    float acc[NHEADS][4] = {};
    float den[NHEADS] = {};

    const float* ctxb  = context + (size_t)b * NN * DD;
    const int*   maskb = mask + (size_t)b * NN;

    for (int n = g; n < NN; n += 8) {
        const float4 c4 = *reinterpret_cast<const float4*>(ctxb + (size_t)n * DD + d4);
        const int m = maskb[n];

        float ps[NHEADS];
        #pragma unroll
        for (int h = 0; h < NHEADS; ++h)
            ps[h] = c4.x * qwr[h][0] + c4.y * qwr[h][1]
                  + c4.z * qwr[h][2] + c4.w * qwr[h][3];

        // butterfly reduce across the 32-lane group (all lanes get the sum)
        #pragma unroll
        for (int off = 16; off >= 1; off >>= 1) {
            #pragma unroll
            for (int h = 0; h < NHEADS; ++h)
                ps[h] += __shfl_xor(ps[h], off, 64);
        }

        #pragma unroll
        for (int h = 0; h < NHEADS; ++h) {
            const float p = m ? 0.f : exp2f(ps[h]);   // scores bounded, no max needed
            den[h] += p;
            acc[h][0] = fmaf(p, c4.x, acc[h][0]);
            acc[h][1] = fmaf(p, c4.y, acc[h][1]);
            acc[h][2] = fmaf(p, c4.z, acc[h][2]);
            acc[h][3] = fmaf(p, c4.w, acc[h][3]);
        }
    }

    // ---- write per-group partials ----
    #pragma unroll
    for (int h = 0; h < NHEADS; ++h)
        *reinterpret_cast<float4*>(&s_acc[g][h][d4]) =
            make_float4(acc[h][0], acc[h][1], acc[h][2], acc[h][3]);
    if (l32 == 0) {
        #pragma unroll
        for (int h = 0; h < NHEADS; ++h) s_den[g][h] = den[h];
    }
    __syncthreads();

    // ---- combine groups: ctx_attn[h][d] = sum_g acc / sum_g den ----
    {
        const int d  = t & 127;
        const int h0 = (t >> 7) * 4;
        for (int hh = 0; hh < 4; ++hh) {
            const int h = h0 + hh;
            float a = 0.f, dn = 0.f;
            #pragma unroll
            for (int gg = 0; gg < 8; ++gg) {
                a  += s_acc[gg][h][d];
                dn += s_den[gg][h];
            }
            s_ca[h][d] = a / dn;
        }
    }
    __syncthreads();

    // ---- out2[r] = ctx_attn[r/16] . Wv[r]  (threads 0..127) ----
    if (t < HH) {
        const int h = t >> 4;
        const float* wvr = Wv + (size_t)t * DD;
        float a = 0.f;
        #pragma unroll 4
        for (int d = 0; d < DD; ++d) a = fmaf(s_ca[h][d], wvr[d], a);
        s_out[t] = a;
    }
    __syncthreads();

    // ---- final[r] = out2 . Wfc[r] ----
    if (t < HH) {
        const float* wfc = Wfc + (size_t)t * DD;
        float a = 0.f;
        #pragma unroll 4
        for (int j = 0; j < DD; ++j) a = fmaf(s_out[j], wfc[j], a);
        out[(size_t)b * HH + t] = a;
    }
}

extern "C" void kernel_launch(void* const* d_in, const int* in_sizes, int n_in,
                              void* d_out, int out_size, void* d_ws, size_t ws_size,
                              hipStream_t stream) {
    const float* state_t = (const float*)d_in[0];
    const float* context = (const float*)d_in[1];
    const int*   mask    = (const int*)d_in[2];
    const float* Wq      = (const float*)d_in[3];
    const float* Wk      = (const float*)d_in[4];
    const float* Wv      = (const float*)d_in[5];
    const float* Wfc     = (const float*)d_in[6];
    float* out = (float*)d_out;

    attn_fused_kernel<<<dim3(NB), dim3(256), 0, stream>>>(
        state_t, context, mask, Wq, Wk, Wv, Wfc, out);
}

// Round 2
// 172.354 us; speedup vs baseline: 1.0463x; 1.0463x over previous
//
#include <hip/hip_runtime.h>

#define NHEADS 8
#define NB 512
#define NN 1000
#define DD 128
#define HH 128
#define SDIM 384          // D*CAT
#define NSPLIT 4
#define ROWS_PER (NN / NSPLIT)   // 250

// ---------------- kernel 0: per-batch qw precompute ----------------
// qw[b][h][d] = (scale*log2e) * sum_j (state[b] . Wq[h*16+j]) * Wk[h*16+j][d]
__global__ __launch_bounds__(256) void qw_kernel(
    const float* __restrict__ state_t,   // [B][384]
    const float* __restrict__ Wq,        // [128][384]
    const float* __restrict__ Wk,        // [128][128]
    float* __restrict__ qw)              // [B][8][128]
{
    const int b = blockIdx.x;
    const int t = threadIdx.x;

    __shared__ float s_state[SDIM];
    __shared__ float s_q[HH];
    __shared__ float s_qw[NHEADS][DD];

    for (int i = t; i < SDIM; i += 256) s_state[i] = state_t[(size_t)b * SDIM + i];
    __syncthreads();

    if (t < HH) {
        const float* wq = Wq + (size_t)t * SDIM;
        float a = 0.f;
        #pragma unroll 4
        for (int c = 0; c < SDIM; ++c) a = fmaf(s_state[c], wq[c], a);
        s_q[t] = a;
    }
    __syncthreads();

    {
        const int d  = t & 127;
        const int h0 = (t >> 7) * 4;
        const float sc = 0.0625f * 1.4426950408889634f;  // (1/hd) * log2(e)
        for (int hh = 0; hh < 4; ++hh) {
            const int h = h0 + hh;
            float a = 0.f;
            #pragma unroll
            for (int j = 0; j < 16; ++j)
                a = fmaf(s_q[h * 16 + j], Wk[(size_t)(h * 16 + j) * DD + d], a);
            s_qw[h][d] = a * sc;
        }
    }
    __syncthreads();

    const float* qf = &s_qw[0][0];
    for (int i = t; i < NHEADS * DD; i += 256)
        qw[(size_t)b * NHEADS * DD + i] = qf[i];
}

// ---------------- kernel 1: fused score+softmax-accumulate, split over N ----
// Each block handles (batch b, split s): rows [s*250, (s+1)*250).
// 256 threads = 4 waves = 8 groups of 32 lanes; group owns rows n=base+g step 8.
__global__ __launch_bounds__(256) void attn_partial_kernel(
    const float* __restrict__ context,   // [B][N][128]
    const int*   __restrict__ mask,      // [B][N]
    const float* __restrict__ qw,        // [B][8][128] (pre-scaled)
    float* __restrict__ part_acc,        // [B][NSPLIT][8][128]
    float* __restrict__ part_den)        // [B][NSPLIT][8]
{
    const int s = blockIdx.x;
    const int b = blockIdx.y;
    const int t = threadIdx.x;

    __shared__ float s_acc[4][NHEADS][DD];   // per-wave partials (16 KB)
    __shared__ float s_den[4][NHEADS];

    const int lane = t & 63;
    const int wv   = t >> 6;
    const int l32  = lane & 31;
    const int g    = wv * 2 + (lane >> 5);
    const int d4   = l32 * 4;

    // per-lane qw slice (registers)
    const float* qwb = qw + (size_t)b * NHEADS * DD;
    float qwr[NHEADS][4];
    #pragma unroll
    for (int h = 0; h < NHEADS; ++h) {
        const float4 q4 = *reinterpret_cast<const float4*>(qwb + h * DD + d4);
        qwr[h][0] = q4.x; qwr[h][1] = q4.y; qwr[h][2] = q4.z; qwr[h][3] = q4.w;
    }

    float acc[NHEADS][4] = {};
    float den[NHEADS] = {};

    const float* ctxb  = context + (size_t)b * NN * DD;
    const int*   maskb = mask + (size_t)b * NN;
    const int nend = (s + 1) * ROWS_PER;

    for (int n = s * ROWS_PER + g; n < nend; n += 8) {
        const float4 c4 = *reinterpret_cast<const float4*>(ctxb + (size_t)n * DD + d4);
        const int m = maskb[n];

        float ps[NHEADS];
        #pragma unroll
        for (int h = 0; h < NHEADS; ++h)
            ps[h] = c4.x * qwr[h][0] + c4.y * qwr[h][1]
                  + c4.z * qwr[h][2] + c4.w * qwr[h][3];

        #pragma unroll
        for (int off = 16; off >= 1; off >>= 1) {
            #pragma unroll
            for (int h = 0; h < NHEADS; ++h)
                ps[h] += __shfl_xor(ps[h], off, 64);
        }

        #pragma unroll
        for (int h = 0; h < NHEADS; ++h) {
            const float p = m ? 0.f : exp2f(ps[h]);   // scores bounded (|s|<~2), no max needed
            den[h] += p;
            acc[h][0] = fmaf(p, c4.x, acc[h][0]);
            acc[h][1] = fmaf(p, c4.y, acc[h][1]);
            acc[h][2] = fmaf(p, c4.z, acc[h][2]);
            acc[h][3] = fmaf(p, c4.w, acc[h][3]);
        }
    }

    // fold the two 32-groups within each wave (xor 32)
    #pragma unroll
    for (int h = 0; h < NHEADS; ++h) {
        #pragma unroll
        for (int k = 0; k < 4; ++k)
            acc[h][k] += __shfl_xor(acc[h][k], 32, 64);
        den[h] += __shfl_xor(den[h], 32, 64);
    }

    if (lane < 32) {
        #pragma unroll
        for (int h = 0; h < NHEADS; ++h)
            *reinterpret_cast<float4*>(&s_acc[wv][h][d4]) =
                make_float4(acc[h][0], acc[h][1], acc[h][2], acc[h][3]);
        if (l32 == 0) {
            #pragma unroll
            for (int h = 0; h < NHEADS; ++h) s_den[wv][h] = den[h];
        }
    }
    __syncthreads();

    // combine 4 waves, write block partial to workspace
    if (t < DD) {
        const int d = t;
        #pragma unroll
        for (int h = 0; h < NHEADS; ++h) {
            const float a = s_acc[0][h][d] + s_acc[1][h][d]
                          + s_acc[2][h][d] + s_acc[3][h][d];
            part_acc[(((size_t)b * NSPLIT + s) * NHEADS + h) * DD + d] = a;
        }
    }
    if (t < NHEADS) {
        const float dn = s_den[0][t] + s_den[1][t] + s_den[2][t] + s_den[3][t];
        part_den[((size_t)b * NSPLIT + s) * NHEADS + t] = dn;
    }
}

// ---------------- kernel 2: combine splits + Wv/Wfc projections -------------
__global__ __launch_bounds__(128) void attn_combine_kernel(
    const float* __restrict__ part_acc,  // [B][NSPLIT][8][128]
    const float* __restrict__ part_den,  // [B][NSPLIT][8]
    const float* __restrict__ Wv,        // [128][128]
    const float* __restrict__ Wfc,       // [128][128]
    float* __restrict__ out)             // [B][128]
{
    const int b = blockIdx.x;
    const int t = threadIdx.x;   // 128 threads

    __shared__ float s_dn[NHEADS];
    __shared__ float s_ca[NHEADS][132];  // padded vs 4-way bank conflict
    __shared__ float s_o2[HH];

    if (t < NHEADS) {
        float dn = 0.f;
        #pragma unroll
        for (int sp = 0; sp < NSPLIT; ++sp)
            dn += part_den[((size_t)b * NSPLIT + sp) * NHEADS + t];
        s_dn[t] = dn;
    }
    __syncthreads();

    {
        const int d = t;
        #pragma unroll
        for (int h = 0; h < NHEADS; ++h) {
            float a = 0.f;
            #pragma unroll
            for (int sp = 0; sp < NSPLIT; ++sp)
                a += part_acc[(((size_t)b * NSPLIT + sp) * NHEADS + h) * DD + d];
            s_ca[h][d] = a / s_dn[h];
        }
    }
    __syncthreads();

    {
        const int h = t >> 4;
        const float* wvr = Wv + (size_t)t * DD;
        float a = 0.f;
        #pragma unroll 4
        for (int d = 0; d < DD; ++d) a = fmaf(s_ca[h][d], wvr[d], a);
        s_o2[t] = a;
    }
    __syncthreads();

    {
        const float* wfc = Wfc + (size_t)t * DD;
        float a = 0.f;
        #pragma unroll 4
        for (int j = 0; j < DD; ++j) a = fmaf(s_o2[j], wfc[j], a);
        out[(size_t)b * HH + t] = a;
    }
}

extern "C" void kernel_launch(void* const* d_in, const int* in_sizes, int n_in,
                              void* d_out, int out_size, void* d_ws, size_t ws_size,
                              hipStream_t stream) {
    const float* state_t = (const float*)d_in[0];
    const float* context = (const float*)d_in[1];
    const int*   mask    = (const int*)d_in[2];
    const float* Wq      = (const float*)d_in[3];
    const float* Wk      = (const float*)d_in[4];
    const float* Wv      = (const float*)d_in[5];
    const float* Wfc     = (const float*)d_in[6];
    float* out = (float*)d_out;

    float* qw       = (float*)d_ws;                                   // 2 MB
    float* part_acc = qw + (size_t)NB * NHEADS * DD;                  // 8 MB
    float* part_den = part_acc + (size_t)NB * NSPLIT * NHEADS * DD;   // 64 KB

    qw_kernel<<<dim3(NB), dim3(256), 0, stream>>>(state_t, Wq, Wk, qw);
    attn_partial_kernel<<<dim3(NSPLIT, NB), dim3(256), 0, stream>>>(
        context, mask, qw, part_acc, part_den);
    attn_combine_kernel<<<dim3(NB), dim3(128), 0, stream>>>(
        part_acc, part_den, Wv, Wfc, out);
}

// Round 3
// 171.207 us; speedup vs baseline: 1.0533x; 1.0067x over previous
//
#include <hip/hip_runtime.h>

#define NHEADS 8
#define NB 512
#define NN 1000
#define DD 128
#define HH 128
#define SDIM 384              // D*CAT
#define NSPLIT 5
#define ROWS_PER (NN / NSPLIT)   // 200 -> 25 iters of 8 rows, no tail

// DPP helper: x += lane-permuted x. Pure VALU (v_mov_b32_dpp + v_add_f32), no DS pipe.
template <int CTRL>
__device__ __forceinline__ float dpp_add(float x) {
    int y = __builtin_amdgcn_update_dpp(0, __float_as_int(x), CTRL, 0xf, 0xf, true);
    return x + __int_as_float(y);
}
#define DPP_QUAD_XOR1 0xB1   // quad_perm(1,0,3,2)
#define DPP_QUAD_XOR2 0x4E   // quad_perm(2,3,0,1)
#define DPP_HALF_MIRR 0x141  // row_half_mirror: lane p -> 7-p within each 8

// ---------------- kernel 0: per-batch qw precompute (coalesced) -------------
// qw[b][h][d] = (scale*log2e) * sum_j (state[b].Wq[h*16+j]) * Wk[h*16+j][d]
__global__ __launch_bounds__(256) void qw_kernel(
    const float* __restrict__ state_t,   // [B][384]
    const float* __restrict__ Wq,        // [128][384]
    const float* __restrict__ Wk,        // [128][128]
    float* __restrict__ qw)              // [B][8][128]
{
    const int b = blockIdx.x;
    const int t = threadIdx.x;
    const int lane = t & 63;
    const int w = t >> 6;

    __shared__ float s_q[HH];

    // phase A: q[r] = state . Wq[r], coalesced mod-64 columns + wave butterfly
    float st[6];
    #pragma unroll
    for (int j = 0; j < 6; ++j) st[j] = state_t[(size_t)b * SDIM + j * 64 + lane];

    for (int it = 0; it < 16; ++it) {
        const int r0 = w * 32 + it * 2;
        const float* w0 = Wq + (size_t)r0 * SDIM;
        const float* w1 = w0 + SDIM;
        float p0 = 0.f, p1 = 0.f;
        #pragma unroll
        for (int j = 0; j < 6; ++j) {
            p0 = fmaf(w0[j * 64 + lane], st[j], p0);
            p1 = fmaf(w1[j * 64 + lane], st[j], p1);
        }
        #pragma unroll
        for (int off = 32; off >= 1; off >>= 1) {
            p0 += __shfl_xor(p0, off, 64);
            p1 += __shfl_xor(p1, off, 64);
        }
        if (lane == 0) { s_q[r0] = p0; s_q[r0 + 1] = p1; }
    }
    __syncthreads();

    // phase B: qw[h][d], coalesced in d
    {
        const int d  = t & 127;
        const int h0 = (t >> 7) * 4;
        const float sc = 0.0625f * 1.4426950408889634f;  // (1/hd) * log2(e)
        for (int hh = 0; hh < 4; ++hh) {
            const int h = h0 + hh;
            float a = 0.f;
            #pragma unroll
            for (int j = 0; j < 16; ++j)
                a = fmaf(s_q[h * 16 + j], Wk[(size_t)(h * 16 + j) * DD + d], a);
            qw[(size_t)b * NHEADS * DD + h * DD + d] = a * sc;
        }
    }
}

// ---------------- kernel 1: fused score+softmax-accumulate ------------------
// Block = (split s, batch b), 256 threads = 4 waves.
// Wave layout: 8 octets of 8 lanes. octet o: head-pair hp=o&3, row-half=o>>2.
// Lane i (in octet) owns d-slice [i*16, i*16+16). Reduction = 3 DPP adds.
__global__ __launch_bounds__(256) void attn_partial_kernel(
    const float* __restrict__ context,   // [B][N][128]
    const int*   __restrict__ mask,      // [B][N]
    const float* __restrict__ qw,        // [B][8][128] (pre-scaled)
    float* __restrict__ part_acc,        // [B][NSPLIT][8][128]
    float* __restrict__ part_den)        // [B][NSPLIT][8]
{
    const int s = blockIdx.x;
    const int b = blockIdx.y;
    const int t = threadIdx.x;
    const int lane = t & 63;
    const int w    = t >> 6;
    const int o    = lane >> 3;
    const int i    = lane & 7;
    const int hp   = o & 3;
    const int half = o >> 2;

    __shared__ float s_acc[8][NHEADS][DD];  // [w*2+half][h][d], 16 KB
    __shared__ float s_den[8][NHEADS];

    // qw slices for heads 2hp, 2hp+1 (32 regs)
    const float* qwb = qw + (size_t)b * NHEADS * DD;
    float q0[16], q1[16];
    #pragma unroll
    for (int k = 0; k < 4; ++k) {
        const float4 a0 = *reinterpret_cast<const float4*>(qwb + (2 * hp) * DD + i * 16 + k * 4);
        const float4 a1 = *reinterpret_cast<const float4*>(qwb + (2 * hp + 1) * DD + i * 16 + k * 4);
        q0[k*4+0]=a0.x; q0[k*4+1]=a0.y; q0[k*4+2]=a0.z; q0[k*4+3]=a0.w;
        q1[k*4+0]=a1.x; q1[k*4+1]=a1.y; q1[k*4+2]=a1.z; q1[k*4+3]=a1.w;
    }

    float acc0[16] = {}, acc1[16] = {};
    float den0 = 0.f, den1 = 0.f;

    const float* ctxb  = context + (size_t)b * NN * DD;
    const int*   maskb = mask + (size_t)b * NN;

    int row = s * ROWS_PER + w * 2 + half;
    #pragma unroll 2
    for (int it = 0; it < ROWS_PER / 8; ++it, row += 8) {
        const float* cp = ctxb + (size_t)row * DD + i * 16;
        float c[16];
        #pragma unroll
        for (int k = 0; k < 4; ++k) {
            const float4 c4 = *reinterpret_cast<const float4*>(cp + k * 4);
            c[k*4+0]=c4.x; c[k*4+1]=c4.y; c[k*4+2]=c4.z; c[k*4+3]=c4.w;
        }
        const int m = maskb[row];

        float ps0 = c[0] * q0[0], ps1 = c[0] * q1[0];
        #pragma unroll
        for (int k = 1; k < 16; ++k) {
            ps0 = fmaf(c[k], q0[k], ps0);
            ps1 = fmaf(c[k], q1[k], ps1);
        }
        // octet all-reduce, pure VALU
        ps0 = dpp_add<DPP_QUAD_XOR1>(ps0); ps1 = dpp_add<DPP_QUAD_XOR1>(ps1);
        ps0 = dpp_add<DPP_QUAD_XOR2>(ps0); ps1 = dpp_add<DPP_QUAD_XOR2>(ps1);
        ps0 = dpp_add<DPP_HALF_MIRR>(ps0); ps1 = dpp_add<DPP_HALF_MIRR>(ps1);

        const float p0 = m ? 0.f : exp2f(ps0);   // scores bounded, no max-sub needed
        const float p1 = m ? 0.f : exp2f(ps1);
        den0 += p0; den1 += p1;
        #pragma unroll
        for (int k = 0; k < 16; ++k) {
            acc0[k] = fmaf(p0, c[k], acc0[k]);
            acc1[k] = fmaf(p1, c[k], acc1[k]);
        }
    }

    // epilogue: each (w,half) slot writes its 2 heads' 16-float slices
    const int slot = w * 2 + half;
    #pragma unroll
    for (int k = 0; k < 4; ++k) {
        *reinterpret_cast<float4*>(&s_acc[slot][2 * hp][i * 16 + k * 4]) =
            make_float4(acc0[k*4+0], acc0[k*4+1], acc0[k*4+2], acc0[k*4+3]);
        *reinterpret_cast<float4*>(&s_acc[slot][2 * hp + 1][i * 16 + k * 4]) =
            make_float4(acc1[k*4+0], acc1[k*4+1], acc1[k*4+2], acc1[k*4+3]);
    }
    if (i == 0) { s_den[slot][2 * hp] = den0; s_den[slot][2 * hp + 1] = den1; }
    __syncthreads();

    if (t < DD) {
        const int d = t;
        #pragma unroll
        for (int h = 0; h < NHEADS; ++h) {
            float a = 0.f;
            #pragma unroll
            for (int sl = 0; sl < 8; ++sl) a += s_acc[sl][h][d];
            part_acc[(((size_t)b * NSPLIT + s) * NHEADS + h) * DD + d] = a;
        }
    }
    if (t < NHEADS) {
        float dn = 0.f;
        #pragma unroll
        for (int sl = 0; sl < 8; ++sl) dn += s_den[sl][t];
        part_den[((size_t)b * NSPLIT + s) * NHEADS + t] = dn;
    }
}

// ---------------- kernel 2: combine splits + Wv/Wfc projections -------------
__global__ __launch_bounds__(128) void attn_combine_kernel(
    const float* __restrict__ part_acc,  // [B][NSPLIT][8][128]
    const float* __restrict__ part_den,  // [B][NSPLIT][8]
    const float* __restrict__ Wv,        // [128][128]
    const float* __restrict__ Wfc,       // [128][128]
    float* __restrict__ out)             // [B][128]
{
    const int b = blockIdx.x;
    const int t = threadIdx.x;   // 128 threads

    __shared__ float s_dn[NHEADS];
    __shared__ float s_ca[NHEADS][132];
    __shared__ float s_o2[HH];

    if (t < NHEADS) {
        float dn = 0.f;
        #pragma unroll
        for (int sp = 0; sp < NSPLIT; ++sp)
            dn += part_den[((size_t)b * NSPLIT + sp) * NHEADS + t];
        s_dn[t] = dn;
    }
    __syncthreads();

    {
        const int d = t;
        #pragma unroll
        for (int h = 0; h < NHEADS; ++h) {
            float a = 0.f;
            #pragma unroll
            for (int sp = 0; sp < NSPLIT; ++sp)
                a += part_acc[(((size_t)b * NSPLIT + sp) * NHEADS + h) * DD + d];
            s_ca[h][d] = a / s_dn[h];
        }
    }
    __syncthreads();

    {
        const int h = t >> 4;
        const float* wvr = Wv + (size_t)t * DD;
        float a = 0.f;
        #pragma unroll 4
        for (int d = 0; d < DD; ++d) a = fmaf(s_ca[h][d], wvr[d], a);
        s_o2[t] = a;
    }
    __syncthreads();

    {
        const float* wfc = Wfc + (size_t)t * DD;
        float a = 0.f;
        #pragma unroll 4
        for (int j = 0; j < DD; ++j) a = fmaf(s_o2[j], wfc[j], a);
        out[(size_t)b * HH + t] = a;
    }
}

extern "C" void kernel_launch(void* const* d_in, const int* in_sizes, int n_in,
                              void* d_out, int out_size, void* d_ws, size_t ws_size,
                              hipStream_t stream) {
    const float* state_t = (const float*)d_in[0];
    const float* context = (const float*)d_in[1];
    const int*   mask    = (const int*)d_in[2];
    const float* Wq      = (const float*)d_in[3];
    const float* Wk      = (const float*)d_in[4];
    const float* Wv      = (const float*)d_in[5];
    const float* Wfc     = (const float*)d_in[6];
    float* out = (float*)d_out;

    float* qw       = (float*)d_ws;                                   // 2 MB
    float* part_acc = qw + (size_t)NB * NHEADS * DD;                  // 10.5 MB
    float* part_den = part_acc + (size_t)NB * NSPLIT * NHEADS * DD;

    qw_kernel<<<dim3(NB), dim3(256), 0, stream>>>(state_t, Wq, Wk, qw);
    attn_partial_kernel<<<dim3(NSPLIT, NB), dim3(256), 0, stream>>>(
        context, mask, qw, part_acc, part_den);
    attn_combine_kernel<<<dim3(NB), dim3(128), 0, stream>>>(
        part_acc, part_den, Wv, Wfc, out);
}

// Round 4
// 136.329 us; speedup vs baseline: 1.3228x; 1.2558x over previous
//
#include <hip/hip_runtime.h>

#define NHEADS 8
#define NB 512
#define NN 1000
#define DD 128
#define HH 128
#define SDIM 384              // D*CAT
#define NSPLIT 10             // blocks per batch (grid.x)
#define NSLOT (NSPLIT * 2)    // one partial slot per wave
#define RPW 50                // rows per wave

// DPP helper: x += lane-permuted x. Pure VALU, no DS pipe.
template <int CTRL>
__device__ __forceinline__ float dpp_add(float x) {
    int y = __builtin_amdgcn_update_dpp(0, __float_as_int(x), CTRL, 0xf, 0xf, true);
    return x + __int_as_float(y);
}
#define DPP_QUAD_XOR1 0xB1   // quad_perm(1,0,3,2)
#define DPP_QUAD_XOR2 0x4E   // quad_perm(2,3,0,1)
#define DPP_HALF_MIRR 0x141  // mirror within 8  (== xor4 after lower folds)
#define DPP_ROW_MIRR  0x140  // mirror within 16 (== xor8 after lower folds)

// ---------------- kernel 0: per-batch qw precompute (coalesced) -------------
__global__ __launch_bounds__(256) void qw_kernel(
    const float* __restrict__ state_t,   // [B][384]
    const float* __restrict__ Wq,        // [128][384]
    const float* __restrict__ Wk,        // [128][128]
    float* __restrict__ qw)              // [B][8][128]
{
    const int b = blockIdx.x;
    const int t = threadIdx.x;
    const int lane = t & 63;
    const int w = t >> 6;

    __shared__ float s_q[HH];

    float st[6];
    #pragma unroll
    for (int j = 0; j < 6; ++j) st[j] = state_t[(size_t)b * SDIM + j * 64 + lane];

    for (int it = 0; it < 16; ++it) {
        const int r0 = w * 32 + it * 2;
        const float* w0 = Wq + (size_t)r0 * SDIM;
        const float* w1 = w0 + SDIM;
        float p0 = 0.f, p1 = 0.f;
        #pragma unroll
        for (int j = 0; j < 6; ++j) {
            p0 = fmaf(w0[j * 64 + lane], st[j], p0);
            p1 = fmaf(w1[j * 64 + lane], st[j], p1);
        }
        #pragma unroll
        for (int off = 32; off >= 1; off >>= 1) {
            p0 += __shfl_xor(p0, off, 64);
            p1 += __shfl_xor(p1, off, 64);
        }
        if (lane == 0) { s_q[r0] = p0; s_q[r0 + 1] = p1; }
    }
    __syncthreads();

    {
        const int d  = t & 127;
        const int h0 = (t >> 7) * 4;
        const float sc = 0.0625f * 1.4426950408889634f;  // (1/hd) * log2(e)
        for (int hh = 0; hh < 4; ++hh) {
            const int h = h0 + hh;
            float a = 0.f;
            #pragma unroll
            for (int j = 0; j < 16; ++j)
                a = fmaf(s_q[h * 16 + j], Wk[(size_t)(h * 16 + j) * DD + d], a);
            qw[(size_t)b * NHEADS * DD + h * DD + d] = a * sc;
        }
    }
}

// ---------------- kernel 1: fused score+softmax-accumulate ------------------
// Block = (split s, batch b), 128 threads = 2 waves, each wave = own 50 rows,
// own output slot. Wave layout: 4 groups of 16 lanes; group g = head pair
// (2g, 2g+1); lane j in group owns floats [j*8, j*8+8) of the row. All 4
// groups load the same row (coalescer merges duplicates). No LDS, no barriers.
__global__ __launch_bounds__(128, 6) void attn_partial_kernel(
    const float* __restrict__ context,   // [B][N][128]
    const int*   __restrict__ mask,      // [B][N]
    const float* __restrict__ qw,        // [B][8][128] (pre-scaled)
    float* __restrict__ part_acc,        // [B][NSLOT][8][128]
    float* __restrict__ part_den)        // [B][NSLOT][8]
{
    const int s = blockIdx.x;
    const int b = blockIdx.y;
    const int w = threadIdx.x >> 6;
    const int lane = threadIdx.x & 63;
    const int g = lane >> 4;     // head pair
    const int j = lane & 15;     // d-slice

    // qw slices for heads 2g, 2g+1 (16 regs)
    const float* qwb = qw + (size_t)b * NHEADS * DD + j * 8;
    const float4 qa0 = *reinterpret_cast<const float4*>(qwb + (2 * g) * DD);
    const float4 qa1 = *reinterpret_cast<const float4*>(qwb + (2 * g) * DD + 4);
    const float4 qb0 = *reinterpret_cast<const float4*>(qwb + (2 * g + 1) * DD);
    const float4 qb1 = *reinterpret_cast<const float4*>(qwb + (2 * g + 1) * DD + 4);

    float4 A0 = make_float4(0.f, 0.f, 0.f, 0.f), A1 = A0;  // acc head 2g
    float4 B0 = A0, B1 = A0;                                // acc head 2g+1
    float den0 = 0.f, den1 = 0.f;

    const int row0 = s * (2 * RPW) + w * RPW;
    const float* cp = context + ((size_t)b * NN + row0) * DD + j * 8;
    const int*   mp = mask + (size_t)b * NN + row0;

    float4 c0 = *reinterpret_cast<const float4*>(cp);
    float4 c1 = *reinterpret_cast<const float4*>(cp + 4);
    int m = mp[0];

    #pragma unroll 2
    for (int it = 0; it < RPW; ++it) {
        float4 n0, n1; int mn;
        const bool more = (it + 1 < RPW);
        if (more) {
            const float* np = cp + (size_t)(it + 1) * DD;
            n0 = *reinterpret_cast<const float4*>(np);
            n1 = *reinterpret_cast<const float4*>(np + 4);
            mn = mp[it + 1];
        }

        // scores for the 2 heads over this lane's 8 floats
        float ps0 = c0.x * qa0.x, ps1 = c0.x * qb0.x;
        ps0 = fmaf(c0.y, qa0.y, ps0); ps1 = fmaf(c0.y, qb0.y, ps1);
        ps0 = fmaf(c0.z, qa0.z, ps0); ps1 = fmaf(c0.z, qb0.z, ps1);
        ps0 = fmaf(c0.w, qa0.w, ps0); ps1 = fmaf(c0.w, qb0.w, ps1);
        ps0 = fmaf(c1.x, qa1.x, ps0); ps1 = fmaf(c1.x, qb1.x, ps1);
        ps0 = fmaf(c1.y, qa1.y, ps0); ps1 = fmaf(c1.y, qb1.y, ps1);
        ps0 = fmaf(c1.z, qa1.z, ps0); ps1 = fmaf(c1.z, qb1.z, ps1);
        ps0 = fmaf(c1.w, qa1.w, ps0); ps1 = fmaf(c1.w, qb1.w, ps1);

        // 16-lane all-reduce: 4 DPP adds per head, two independent chains
        ps0 = dpp_add<DPP_QUAD_XOR1>(ps0); ps1 = dpp_add<DPP_QUAD_XOR1>(ps1);
        ps0 = dpp_add<DPP_QUAD_XOR2>(ps0); ps1 = dpp_add<DPP_QUAD_XOR2>(ps1);
        ps0 = dpp_add<DPP_HALF_MIRR>(ps0); ps1 = dpp_add<DPP_HALF_MIRR>(ps1);
        ps0 = dpp_add<DPP_ROW_MIRR>(ps0);  ps1 = dpp_add<DPP_ROW_MIRR>(ps1);

        const float p0 = m ? 0.f : exp2f(ps0);   // scores bounded, no max-sub
        const float p1 = m ? 0.f : exp2f(ps1);
        den0 += p0; den1 += p1;

        A0.x = fmaf(p0, c0.x, A0.x); B0.x = fmaf(p1, c0.x, B0.x);
        A0.y = fmaf(p0, c0.y, A0.y); B0.y = fmaf(p1, c0.y, B0.y);
        A0.z = fmaf(p0, c0.z, A0.z); B0.z = fmaf(p1, c0.z, B0.z);
        A0.w = fmaf(p0, c0.w, A0.w); B0.w = fmaf(p1, c0.w, B0.w);
        A1.x = fmaf(p0, c1.x, A1.x); B1.x = fmaf(p1, c1.x, B1.x);
        A1.y = fmaf(p0, c1.y, A1.y); B1.y = fmaf(p1, c1.y, B1.y);
        A1.z = fmaf(p0, c1.z, A1.z); B1.z = fmaf(p1, c1.z, B1.z);
        A1.w = fmaf(p0, c1.w, A1.w); B1.w = fmaf(p1, c1.w, B1.w);

        c0 = n0; c1 = n1; m = mn;
    }

    // epilogue: each wave writes its own slot — no LDS, no barrier
    const int slot = s * 2 + w;
    float* pa = part_acc + (((size_t)b * NSLOT + slot) * NHEADS) * DD + j * 8;
    *reinterpret_cast<float4*>(pa + (2 * g) * DD)         = A0;
    *reinterpret_cast<float4*>(pa + (2 * g) * DD + 4)     = A1;
    *reinterpret_cast<float4*>(pa + (2 * g + 1) * DD)     = B0;
    *reinterpret_cast<float4*>(pa + (2 * g + 1) * DD + 4) = B1;
    if (j == 0) {
        float* pd = part_den + ((size_t)b * NSLOT + slot) * NHEADS;
        pd[2 * g]     = den0;
        pd[2 * g + 1] = den1;
    }
}

// ---------------- kernel 2: combine slots + Wv/Wfc projections --------------
__global__ __launch_bounds__(128) void attn_combine_kernel(
    const float* __restrict__ part_acc,  // [B][NSLOT][8][128]
    const float* __restrict__ part_den,  // [B][NSLOT][8]
    const float* __restrict__ Wv,        // [128][128]
    const float* __restrict__ Wfc,       // [128][128]
    float* __restrict__ out)             // [B][128]
{
    const int b = blockIdx.x;
    const int t = threadIdx.x;   // 128 threads

    __shared__ float s_dn[NHEADS];
    __shared__ float s_ca[NHEADS][132];
    __shared__ float s_o2[HH];

    if (t < NHEADS) {
        float dn = 0.f;
        #pragma unroll
        for (int sp = 0; sp < NSLOT; ++sp)
            dn += part_den[((size_t)b * NSLOT + sp) * NHEADS + t];
        s_dn[t] = dn;
    }
    __syncthreads();

    {
        const int d = t;
        #pragma unroll
        for (int h = 0; h < NHEADS; ++h) {
            float a = 0.f;
            #pragma unroll
            for (int sp = 0; sp < NSLOT; ++sp)
                a += part_acc[(((size_t)b * NSLOT + sp) * NHEADS + h) * DD + d];
            s_ca[h][d] = a / s_dn[h];
        }
    }
    __syncthreads();

    {
        const int h = t >> 4;
        const float* wvr = Wv + (size_t)t * DD;
        float a = 0.f;
        #pragma unroll 4
        for (int d = 0; d < DD; ++d) a = fmaf(s_ca[h][d], wvr[d], a);
        s_o2[t] = a;
    }
    __syncthreads();

    {
        const float* wfc = Wfc + (size_t)t * DD;
        float a = 0.f;
        #pragma unroll 4
        for (int j = 0; j < DD; ++j) a = fmaf(s_o2[j], wfc[j], a);
        out[(size_t)b * HH + t] = a;
    }
}

extern "C" void kernel_launch(void* const* d_in, const int* in_sizes, int n_in,
                              void* d_out, int out_size, void* d_ws, size_t ws_size,
                              hipStream_t stream) {
    const float* state_t = (const float*)d_in[0];
    const float* context = (const float*)d_in[1];
    const int*   mask    = (const int*)d_in[2];
    const float* Wq      = (const float*)d_in[3];
    const float* Wk      = (const float*)d_in[4];
    const float* Wv      = (const float*)d_in[5];
    const float* Wfc     = (const float*)d_in[6];
    float* out = (float*)d_out;

    float* qw       = (float*)d_ws;                                  // 2 MB
    float* part_acc = qw + (size_t)NB * NHEADS * DD;                 // 42 MB
    float* part_den = part_acc + (size_t)NB * NSLOT * NHEADS * DD;   // 0.3 MB

    qw_kernel<<<dim3(NB), dim3(256), 0, stream>>>(state_t, Wq, Wk, qw);
    attn_partial_kernel<<<dim3(NSPLIT, NB), dim3(128), 0, stream>>>(
        context, mask, qw, part_acc, part_den);
    attn_combine_kernel<<<dim3(NB), dim3(128), 0, stream>>>(
        part_acc, part_den, Wv, Wfc, out);
}